// Round 16
// baseline (212.786 us; speedup 1.0000x reference)
//
#include <hip/hip_runtime.h>

typedef _Float16 half8  __attribute__((ext_vector_type(8)));
typedef float    f32x4  __attribute__((ext_vector_type(4)));
typedef unsigned short ushort8 __attribute__((ext_vector_type(8)));

__device__ __forceinline__ float clampf(float v, float lo, float hi){
    return fminf(fmaxf(v, lo), hi);
}
__device__ __forceinline__ float b2f(unsigned short u){
    unsigned int x = ((unsigned int)u) << 16;
    return __builtin_bit_cast(float, x);
}
__device__ __forceinline__ unsigned short f2b(float f){
    unsigned int u = __builtin_bit_cast(unsigned int, f);
    u += 0x7FFFu + ((u >> 16) & 1u);       // round-to-nearest-even
    return (unsigned short)(u >> 16);
}
// raw v_exp_f32 (args bounded |x|<=~80 -> OCML safe path unnecessary)
__device__ __forceinline__ float fexp2(float x){ return __builtin_amdgcn_exp2f(x); }

// async global->LDS staging, 16B/lane (GEMMs only).
__device__ __forceinline__ void gld_lds16(const _Float16* g, _Float16* lds_uniform){
    __builtin_amdgcn_global_load_lds(
        (const __attribute__((address_space(1))) void*)g,
        (__attribute__((address_space(3))) void*)lds_uniform, 16, 0, 0);
}

// ---------------------------------------------------------------------------
// ws layout in _Float16 ELEMENT offsets (all tensors stored as integer-valued f16)
#define EW_WALL 0u                       // [1536][512] packed Wq/Wk/Wv rows
#define EW_WO   786432u                  // [512][512]
#define EW_AQ   1048576u                 // [8192][512] act for q-proj; dead after
                                         //   k_gemm_qkv -> reused: lpart + cmx
#define EW_AK   (EW_AQ + 4194304u)
#define EW_AV   (EW_AK + 4194304u)
#define EW_Q    (EW_AV + 4194304u)       // [bh=32][s=2048][d=64]
#define EW_K    (EW_Q  + 4194304u)       // [bh][s][d]
#define EW_VT   (EW_K  + 4194304u)       // [bh][d=64][s=2048]  (V transposed)
#define EW_O    (EW_VT + 4194304u)       // [8192][512]
// total = 30,408,704 elements = 60,817,408 bytes

// ---------------------------------------------------------------------------
// Merged quantization: blocks 0..511 quantize the 4 weight matrices,
// blocks 512..2559 quantize hs into aq/ak/av (saves one launch).
__global__ __launch_bounds__(256) void k_quant(
    const unsigned short* __restrict__ hs,
    const unsigned short* __restrict__ Wq, const unsigned short* __restrict__ Wk,
    const unsigned short* __restrict__ Wv, const unsigned short* __restrict__ Wo,
    _Float16* __restrict__ w_all, _Float16* __restrict__ wo16,
    _Float16* __restrict__ aq, _Float16* __restrict__ ak, _Float16* __restrict__ av,
    const unsigned short* __restrict__ scu)
{
    int blk = blockIdx.x;
    if (blk < 512){
        int gid  = blk * 256 + threadIdx.x;          // 131072 threads, 8 elems
        int idx8 = gid * 8;
        int which = idx8 >> 18;                      // 262144 elems per matrix
        int rem   = idx8 & 262143;
        const unsigned short* W = (which==0)? Wq : (which==1)? Wk : (which==2)? Wv : Wo;
        float sw = b2f((which<3) ? scu[2 + 2*which] : scu[13]);
        ushort8 w = *(const ushort8*)(W + rem);
        half8 o;
        #pragma unroll
        for (int j=0;j<8;j++)
            o[j] = (_Float16)rintf(clampf(b2f(w[j])/sw, -128.f, 127.f));
        _Float16* dst = (which<3) ? (w_all + which*262144 + rem) : (wo16 + rem);
        *(half8*)dst = o;
    } else {
        int gid = (blk - 512) * 256 + threadIdx.x;   // 524288 threads, 8 elems
        int i8 = gid * 8;
        float s0 = b2f(scu[0]), s1 = b2f(scu[1]), s3 = b2f(scu[3]), s5 = b2f(scu[5]);
        ushort8 h = *(const ushort8*)(hs + i8);
        half8 q, k, v;
        #pragma unroll
        for (int j=0;j<8;j++){
            float h1 = rintf(clampf(b2f(h[j])/s0, -128.f, 127.f)) * s0;  // fq(hs,s0)
            q[j] = (_Float16)rintf(clampf(h1/s1, -128.f, 127.f));
            k[j] = (_Float16)rintf(clampf(h1/s3, -128.f, 127.f));
            v[j] = (_Float16)rintf(clampf(h1/s5, -128.f, 127.f));
        }
        *(half8*)(aq+i8) = q;
        *(half8*)(ak+i8) = k;
        *(half8*)(av+i8) = v;
    }
}

// ---------------------------------------------------------------------------
// QKV projection: M=8192, N=1536, K=512. 128x64 tiles, grid (64,24) = 1536
// blocks = 6 blocks/CU. V (proj==2) epilogue via LDS transpose (coalesced).
__global__ __launch_bounds__(256) void k_gemm_qkv(
    const _Float16* __restrict__ aq, const _Float16* __restrict__ ak,
    const _Float16* __restrict__ av, const _Float16* __restrict__ w_all,
    _Float16* __restrict__ q16, _Float16* __restrict__ k16, _Float16* __restrict__ vt16,
    const unsigned short* __restrict__ scu)
{
    __shared__ __align__(16) union SMem {
        struct { _Float16 At[128][64]; _Float16 Bt[64][64]; } ab;
        _Float16 Vt[64][132];            // +4 pad: conflict-free transpose
    } sm;
    int tid = threadIdx.x;
    int m0 = blockIdx.x*128, n0 = blockIdx.y*64;
    int proj = blockIdx.y >> 3;                  // 8 n-blocks of 64 per projection
    const _Float16* Ag = (proj==0)? aq : (proj==1)? ak : av;
    int w = tid>>6, lane = tid&63, l15 = lane&15, quad = lane>>4;
    int wm = w>>1, wn = w&1;
    f32x4 z = {0.f,0.f,0.f,0.f};
    f32x4 acc[4][2];
    #pragma unroll
    for (int i=0;i<4;i++)
      #pragma unroll
      for (int j=0;j<2;j++) acc[i][j] = z;

    for (int k0=0; k0<512; k0+=64){
        #pragma unroll
        for (int it=0; it<4; it++){          // A: 128x64 halves = 1024 x 16B
            int idx = it*256 + tid;
            int row = idx>>3, col = (idx&7)*8;
            int ubase = (it*256 + w*64)*8;   // wave-uniform LDS half-offset
            gld_lds16(Ag + (m0+row)*512 + k0 + col, &sm.ab.At[0][0] + ubase);
        }
        #pragma unroll
        for (int it=0; it<2; it++){          // B: 64x64 halves = 512 x 16B
            int idx = it*256 + tid;
            int row = idx>>3, col = (idx&7)*8;
            int ubase = (it*256 + w*64)*8;
            gld_lds16(w_all + (n0+row)*512 + k0 + col, &sm.ab.Bt[0][0] + ubase);
        }
        __syncthreads();
        half8 af[4][2], bf[2][2];
        #pragma unroll
        for (int mt=0; mt<4; mt++){
            af[mt][0] = *(const half8*)(&sm.ab.At[wm*64+mt*16+l15][quad*8]);
            af[mt][1] = *(const half8*)(&sm.ab.At[wm*64+mt*16+l15][32+quad*8]);
        }
        #pragma unroll
        for (int nt=0; nt<2; nt++){
            bf[nt][0] = *(const half8*)(&sm.ab.Bt[wn*32+nt*16+l15][quad*8]);
            bf[nt][1] = *(const half8*)(&sm.ab.Bt[wn*32+nt*16+l15][32+quad*8]);
        }
        #pragma unroll
        for (int mt=0; mt<4; mt++)
          #pragma unroll
          for (int nt=0; nt<2; nt++){
            acc[mt][nt] = __builtin_amdgcn_mfma_f32_16x16x32_f16(af[mt][0], bf[nt][0], acc[mt][nt], 0,0,0);
            acc[mt][nt] = __builtin_amdgcn_mfma_f32_16x16x32_f16(af[mt][1], bf[nt][1], acc[mt][nt], 0,0,0);
          }
        __syncthreads();
    }

    float ssc = b2f(scu[1+2*proj]) * b2f(scu[2+2*proj]);
    float qs  = b2f((proj==0)? scu[7] : (proj==1)? scu[8] : scu[11]);
    if (proj < 2){
        #pragma unroll
        for (int mt=0; mt<4; mt++){
          #pragma unroll
          for (int nt=0; nt<2; nt++){
            int n = n0 + wn*32 + nt*16 + l15;        // C/D col = lane&15 (verified)
            int nloc = n & 511;
            int h = nloc>>6, d = nloc&63;
            #pragma unroll
            for (int r=0;r<4;r++){
              int m = m0 + wm*64 + mt*16 + quad*4 + r;   // C/D row = quad*4+reg
              int b = m>>11, s = m&2047;
              int bh = b*8 + h;
              float val = acc[mt][nt][r] * ssc;
              float qv = rintf(clampf(val/qs, -128.f, 127.f));
              if (proj==0) q16[(bh*2048 + s)*64 + d] = (_Float16)qv;
              else         k16[(bh*2048 + s)*64 + d] = (_Float16)qv;
            }
          }
        }
    } else {
        // stage quantized V-tile into LDS transposed: Vt[n_local][m_local]
        #pragma unroll
        for (int mt=0; mt<4; mt++){
          #pragma unroll
          for (int nt=0; nt<2; nt++){
            int nl = wn*32 + nt*16 + l15;            // n-local 0..63
            #pragma unroll
            for (int r=0;r<4;r++){
              int ml = wm*64 + mt*16 + quad*4 + r;   // m-local 0..127
              float val = acc[mt][nt][r] * ssc;
              sm.Vt[nl][ml] = (_Float16)rintf(clampf(val/qs, -128.f, 127.f));
            }
          }
        }
        __syncthreads();
        int vrow = tid >> 2;                 // 0..63 (n-local)
        int vcol = (tid & 3) * 32;           // m-local base
        int nloc2 = (n0 & 511) + vrow;
        int h2 = nloc2 >> 6, d2 = nloc2 & 63;
        int bh2 = (m0 >> 11)*8 + h2;
        int s2 = (m0 & 2047) + vcol;
        _Float16* dst = vt16 + (bh2*64 + d2)*2048 + s2;
        #pragma unroll
        for (int i=0;i<4;i++)
            *(half8*)(dst + i*8) = *(const half8*)(&sm.Vt[vrow][vcol + i*8]);
    }
}

// ---------------------------------------------------------------------------
// Attention pass 1, t-split x4: block = (bh, 64 q-rows, 512-t quarter);
// grid 4096; LDS 18.4 KB -> LB(256,6) = 6 blocks/CU = 24 waves/CU (+50% TLP
// vs the fused kernel's work-limited 16). Writes partial denominators lpart
// (4 disjoint quarter slots, R12-verified exact scheme) AND per-chunk wave-max
// raw scores cmxg (for the R15 provable skip mask). No state carried to pv.
__global__ __launch_bounds__(256, 6) void k_attn_l(
    const _Float16* __restrict__ q16, const _Float16* __restrict__ k16,
    float* __restrict__ lpart, float* __restrict__ cmxg,
    const unsigned short* __restrict__ scu)
{
    __shared__ __align__(16) _Float16 Kbuf[2][64][72];
    int tid = threadIdx.x;
    int w = tid>>6, lane = tid&63, l15 = lane&15, quad = lane>>4;
    int blk = blockIdx.x;                    // = bh*128 + qg*4 + tq
    int bh = blk >> 7, qg = (blk >> 2) & 31, tq = blk & 3;
    int q0 = qg*64 + w*16;
    float al2 = b2f(scu[7]) * b2f(scu[8]) * 0.125f * 1.44269504088896341f;

    f32x4 z = {0.f,0.f,0.f,0.f};
    const _Float16* qr = q16 + (bh*2048 + q0 + l15)*64;
    half8 aq0 = *(const half8*)(qr + quad*8);
    half8 aq1 = *(const half8*)(qr + 32 + quad*8);

    const _Float16* kg = k16 + bh*131072 + tq*32768;   // quarter base
    int srow = tid>>3, scol = (tid&7)*8;

    half8 kst[2];
    #pragma unroll
    for (int i=0;i<2;i++) kst[i] = *(const half8*)(kg + i*2048 + tid*8);

    float l[4] = {0.f, 0.f, 0.f, 0.f};
    float cmx[8];

    #pragma unroll
    for (int ch=0; ch<8; ch++){
        int buf = ch & 1;
        #pragma unroll
        for (int i=0;i<2;i++) *(half8*)(&Kbuf[buf][srow + i*32][scol]) = kst[i];
        __syncthreads();
        if (ch < 7){                        // prefetch AFTER barrier
            const _Float16* nsrc = kg + (ch+1)*4096;
            #pragma unroll
            for (int i=0;i<2;i++) kst[i] = *(const half8*)(nsrc + i*2048 + tid*8);
        }
        f32x4 s[4];
        #pragma unroll
        for (int j=0;j<4;j++){
            half8 bk0 = *(const half8*)(&Kbuf[buf][j*16+l15][quad*8]);
            half8 bk1 = *(const half8*)(&Kbuf[buf][j*16+l15][32+quad*8]);
            f32x4 t = __builtin_amdgcn_mfma_f32_16x16x32_f16(aq0, bk0, z, 0,0,0);
            s[j]    = __builtin_amdgcn_mfma_f32_16x16x32_f16(aq1, bk1, t, 0,0,0);
        }
        float mx = s[0][0];
        #pragma unroll
        for (int j=0;j<4;j++){
            #pragma unroll
            for (int r=0;r<4;r++){
                mx = fmaxf(mx, s[j][r]);
                l[r] += fexp2(s[j][r]*al2);
            }
        }
        cmx[ch] = mx;
    }

    // row sums: reduce over the 16 column lanes (quad preserved, d<16)
    #pragma unroll
    for (int r=0;r<4;r++){
        #pragma unroll
        for (int d=1; d<16; d<<=1)
            l[r] += __shfl_xor(l[r], d, 64);
    }
    if (l15 == 0){
        #pragma unroll
        for (int r=0;r<4;r++)
            lpart[tq*65536 + bh*2048 + q0 + quad*4 + r] = l[r];
    }
    // chunk maxima: full 64-lane reduce, one scalar per chunk
    int qt = qg*4 + w;
    #pragma unroll
    for (int ch=0; ch<8; ch++){
        float cm = cmx[ch];
        #pragma unroll
        for (int d=1; d<64; d<<=1) cm = fmaxf(cm, __shfl_xor(cm, d, 64));
        if (lane == 0) cmxg[(bh*128 + qt)*32 + tq*8 + ch] = cm;
    }
}

// ---------------------------------------------------------------------------
// Attention pass 2: reads lpart (4 quarters) + cmxg, builds the provable
// zero-P mask (identical bound to R15 — skipped chunks provably quantize to
// all-zero P), then the barrier-free masked loop with direct-global K reads
// (L2-hot from pass 1). Block = 4 waves = (bh, 64 q-rows).
__global__ __launch_bounds__(256, 5) void k_attn_pv(
    const _Float16* __restrict__ q16, const _Float16* __restrict__ k16,
    const _Float16* __restrict__ vt16, const float* __restrict__ lpart,
    const float* __restrict__ cmxg, _Float16* __restrict__ o16,
    const unsigned short* __restrict__ scu)
{
    __shared__ __align__(16) _Float16 p16[4][16][72];
    int tid = threadIdx.x;
    int w = tid>>6, lane = tid&63, l15 = lane&15, quad = lane>>4;
    int bh = blockIdx.y;
    int q0 = blockIdx.x*64 + w*16;
    int qt = blockIdx.x*4 + w;
    float s9 = b2f(scu[9]), s10 = b2f(scu[10]);
    float al2 = b2f(scu[7]) * b2f(scu[8]) * 0.125f * 1.44269504088896341f;

    f32x4 z = {0.f,0.f,0.f,0.f};
    const _Float16* qr = q16 + (bh*2048 + q0 + l15)*64;
    half8 aq0 = *(const half8*)(qr + quad*8);
    half8 aq1 = *(const half8*)(qr + 32 + quad*8);

    float inv_s9 = 1.0f / s9;
    float r910   = s9 / s10;
    float lq9[4];
    #pragma unroll
    for (int r=0;r<4;r++){
        int idx = bh*2048 + q0 + quad*4 + r;
        float ltot = lpart[idx] + lpart[65536+idx] + lpart[131072+idx] + lpart[196608+idx];
        lq9[r] = log2f(inv_s9 / ltot);
    }
    float lm = fmaxf(fmaxf(lq9[0], lq9[1]), fmaxf(lq9[2], lq9[3]));
    lm = fmaxf(lm, __shfl_xor(lm, 16, 64));
    lm = fmaxf(lm, __shfl_xor(lm, 32, 64));

    const float* cmb = cmxg + (bh*128 + qt)*32;
    unsigned int mask = 0u;
    #pragma unroll
    for (int ch=0; ch<32; ch++){
        if (fmaf(cmb[ch], al2, lm) > -1.0001f) mask |= (1u << ch);
    }

    const _Float16* kg    = k16  + bh*131072;
    const _Float16* vbase = vt16 + bh*131072;

    f32x4 oacc[4];
    #pragma unroll
    for (int dt=0; dt<4; dt++) oacc[dt] = z;
    for (int ch=0; ch<32; ch++){
        if (!(mask & (1u << ch))) continue;
        const _Float16* kc = kg + ch*4096;
        f32x4 s[4];
        #pragma unroll
        for (int j=0;j<4;j++){
            const _Float16* kr = kc + (j*16+l15)*64;
            half8 bk0 = *(const half8*)(kr + quad*8);
            half8 bk1 = *(const half8*)(kr + 32 + quad*8);
            f32x4 t = __builtin_amdgcn_mfma_f32_16x16x32_f16(aq0, bk0, z, 0,0,0);
            s[j]    = __builtin_amdgcn_mfma_f32_16x16x32_f16(aq1, bk1, t, 0,0,0);
        }
        float av[4][4];
        float amax = 0.f;
        #pragma unroll
        for (int j=0;j<4;j++){
            #pragma unroll
            for (int r=0;r<4;r++){
                float p1i = rintf(fminf(fexp2(fmaf(s[j][r], al2, lq9[r])), 255.f));
                float a   = rintf(fminf(p1i*r910, 127.f));
                av[j][r] = a;
                amax = fmaxf(amax, a);
            }
        }
        if (__ballot(amax > 0.f)){           // bound not tight: exact re-check
            #pragma unroll
            for (int j=0;j<4;j++)
                #pragma unroll
                for (int r=0;r<4;r++)
                    p16[w][quad*4+r][j*16+l15] = (_Float16)av[j][r];
            half8 ap0 = *(const half8*)(&p16[w][l15][quad*8]);
            half8 ap1 = *(const half8*)(&p16[w][l15][32+quad*8]);
            #pragma unroll
            for (int dt=0; dt<4; dt++){
                const _Float16* vr0 = vbase + (dt*16+l15)*2048 + ch*64;
                half8 b0 = *(const half8*)(vr0 + quad*8);
                half8 b1 = *(const half8*)(vr0 + 32 + quad*8);
                oacc[dt] = __builtin_amdgcn_mfma_f32_16x16x32_f16(ap0, b0, oacc[dt], 0,0,0);
                oacc[dt] = __builtin_amdgcn_mfma_f32_16x16x32_f16(ap1, b1, oacc[dt], 0,0,0);
            }
        }
    }

    float s1011 = b2f(scu[10]) * b2f(scu[11]);
    float s12   = b2f(scu[12]);
    int b = bh>>3, h = bh&7;
    #pragma unroll
    for (int dt=0; dt<4; dt++){
        #pragma unroll
        for (int r=0;r<4;r++){
            float o = oacc[dt][r] * s1011;
            _Float16 v = (_Float16)rintf(clampf(o/s12, -128.f, 127.f));
            o16[(b*2048 + q0 + quad*4 + r)*512 + h*64 + dt*16 + l15] = v;
        }
    }
}

// ---------------------------------------------------------------------------
// Output projection: M=8192, N=512, K=512, + bias, bf16 out. 64x64 tiles.
__global__ __launch_bounds__(256) void k_gemm_out(
    const _Float16* __restrict__ o16, const _Float16* __restrict__ wo16,
    const unsigned short* __restrict__ bo, unsigned short* __restrict__ out,
    const unsigned short* __restrict__ scu)
{
    __shared__ __align__(16) _Float16 At[64][64];
    __shared__ __align__(16) _Float16 Bt[64][64];
    int tid = threadIdx.x;
    int m0 = blockIdx.x*64, n0 = blockIdx.y*64;
    int w = tid>>6, lane = tid&63, l15 = lane&15, quad = lane>>4;
    int wm = w>>1, wn = w&1;
    f32x4 z = {0.f,0.f,0.f,0.f};
    f32x4 acc[2][2];
    #pragma unroll
    for (int i=0;i<2;i++)
      #pragma unroll
      for (int j=0;j<2;j++) acc[i][j] = z;

    for (int k0=0; k0<512; k0+=64){
        #pragma unroll
        for (int it=0; it<2; it++){
            int idx = it*256 + tid;
            int row = idx>>3, col = (idx&7)*8;
            int ubase = (it*256 + w*64)*8;
            gld_lds16(o16  + (m0+row)*512 + k0 + col, &At[0][0] + ubase);
        }
        #pragma unroll
        for (int it=0; it<2; it++){
            int idx = it*256 + tid;
            int row = idx>>3, col = (idx&7)*8;
            int ubase = (it*256 + w*64)*8;
            gld_lds16(wo16 + (n0+row)*512 + k0 + col, &Bt[0][0] + ubase);
        }
        __syncthreads();
        half8 af[2][2], bf[2][2];
        #pragma unroll
        for (int mt=0; mt<2; mt++){
            af[mt][0] = *(const half8*)(&At[wm*32+mt*16+l15][quad*8]);
            af[mt][1] = *(const half8*)(&At[wm*32+mt*16+l15][32+quad*8]);
        }
        #pragma unroll
        for (int nt=0; nt<2; nt++){
            bf[nt][0] = *(const half8*)(&Bt[wn*32+nt*16+l15][quad*8]);
            bf[nt][1] = *(const half8*)(&Bt[wn*32+nt*16+l15][32+quad*8]);
        }
        #pragma unroll
        for (int mt=0; mt<2; mt++)
          #pragma unroll
          for (int nt=0; nt<2; nt++){
            acc[mt][nt] = __builtin_amdgcn_mfma_f32_16x16x32_f16(af[mt][0], bf[nt][0], acc[mt][nt], 0,0,0);
            acc[mt][nt] = __builtin_amdgcn_mfma_f32_16x16x32_f16(af[mt][1], bf[nt][1], acc[mt][nt], 0,0,0);
          }
        __syncthreads();
    }

    float ssc = b2f(scu[12]) * b2f(scu[13]);
    #pragma unroll
    for (int mt=0; mt<2; mt++){
      #pragma unroll
      for (int nt=0; nt<2; nt++){
        int n = n0 + wn*32 + nt*16 + l15;
        float bn = b2f(bo[n]);
        #pragma unroll
        for (int r=0;r<4;r++){
          int m = m0 + wm*32 + mt*16 + quad*4 + r;
          out[m*512 + n] = f2b(acc[mt][nt][r]*ssc + bn);
        }
      }
    }
}

// ---------------------------------------------------------------------------
extern "C" void kernel_launch(void* const* d_in, const int* in_sizes, int n_in,
                              void* d_out, int out_size, void* d_ws, size_t ws_size,
                              hipStream_t stream)
{
    const unsigned short* hs = (const unsigned short*)d_in[0];
    const unsigned short* Wq = (const unsigned short*)d_in[1];
    const unsigned short* Wk = (const unsigned short*)d_in[2];
    const unsigned short* Wv = (const unsigned short*)d_in[3];
    const unsigned short* Wo = (const unsigned short*)d_in[4];
    const unsigned short* bo = (const unsigned short*)d_in[5];
    const unsigned short* sc = (const unsigned short*)d_in[6];
    unsigned short* out = (unsigned short*)d_out;

    _Float16* wsh   = (_Float16*)d_ws;
    _Float16* w_all = wsh + EW_WALL;
    _Float16* wo16  = wsh + EW_WO;
    _Float16* a_q   = wsh + EW_AQ;
    _Float16* a_k   = wsh + EW_AK;
    _Float16* a_v   = wsh + EW_AV;
    _Float16* q16   = wsh + EW_Q;
    _Float16* k16   = wsh + EW_K;
    _Float16* vt16  = wsh + EW_VT;
    _Float16* o16   = wsh + EW_O;
    float*    lpart = (float*)(wsh + EW_AQ);             // dead-aq reuse
    float*    cmxg  = (float*)(wsh + EW_AQ + 524288u);   // after lpart (1 MB)

    k_quant<<<2560, 256, 0, stream>>>(hs, Wq, Wk, Wv, Wo, w_all, wo16,
                                      a_q, a_k, a_v, sc);
    k_gemm_qkv<<<dim3(64,24), 256, 0, stream>>>(a_q, a_k, a_v, w_all, q16, k16, vt16, sc);
    k_attn_l<<<4096, 256, 0, stream>>>(q16, k16, lpart, cmxg, sc);
    k_attn_pv<<<dim3(32,32), 256, 0, stream>>>(q16, k16, vt16, lpart, cmxg, o16, sc);
    k_gemm_out<<<dim3(128,8), 256, 0, stream>>>(o16, wo16, bo, out, sc);
}

// Round 17
// 170.552 us; speedup vs baseline: 1.2476x; 1.2476x over previous
//
#include <hip/hip_runtime.h>

typedef _Float16 half8  __attribute__((ext_vector_type(8)));
typedef float    f32x4  __attribute__((ext_vector_type(4)));
typedef unsigned short ushort8 __attribute__((ext_vector_type(8)));

__device__ __forceinline__ float clampf(float v, float lo, float hi){
    return fminf(fmaxf(v, lo), hi);
}
__device__ __forceinline__ float b2f(unsigned short u){
    unsigned int x = ((unsigned int)u) << 16;
    return __builtin_bit_cast(float, x);
}
__device__ __forceinline__ unsigned short f2b(float f){
    unsigned int u = __builtin_bit_cast(unsigned int, f);
    u += 0x7FFFu + ((u >> 16) & 1u);       // round-to-nearest-even
    return (unsigned short)(u >> 16);
}
// raw v_exp_f32 (args bounded |x|<=~80 -> OCML safe path unnecessary)
__device__ __forceinline__ float fexp2(float x){ return __builtin_amdgcn_exp2f(x); }

// async global->LDS staging, 16B/lane (GEMMs only).
__device__ __forceinline__ void gld_lds16(const _Float16* g, _Float16* lds_uniform){
    __builtin_amdgcn_global_load_lds(
        (const __attribute__((address_space(1))) void*)g,
        (__attribute__((address_space(3))) void*)lds_uniform, 16, 0, 0);
}

// ---------------------------------------------------------------------------
// ws layout in _Float16 ELEMENT offsets (all tensors stored as integer-valued f16)
#define EW_WALL 0u                       // [1536][512] packed Wq/Wk/Wv rows
#define EW_WO   786432u                  // [512][512]
#define EW_AQ   1048576u                 // [8192][512] act for q-proj
#define EW_AK   (EW_AQ + 4194304u)
#define EW_AV   (EW_AK + 4194304u)
#define EW_Q    (EW_AV + 4194304u)       // [bh=32][s=2048][d=64]
#define EW_K    (EW_Q  + 4194304u)       // [bh][s][d]
#define EW_VT   (EW_K  + 4194304u)       // [bh][d=64][s=2048]  (V transposed)
#define EW_O    (EW_VT + 4194304u)       // [8192][512]
// total = 30,408,704 elements = 60,817,408 bytes

// ---------------------------------------------------------------------------
// Merged quantization: blocks 0..511 quantize the 4 weight matrices,
// blocks 512..2559 quantize hs into aq/ak/av (saves one launch).
__global__ __launch_bounds__(256) void k_quant(
    const unsigned short* __restrict__ hs,
    const unsigned short* __restrict__ Wq, const unsigned short* __restrict__ Wk,
    const unsigned short* __restrict__ Wv, const unsigned short* __restrict__ Wo,
    _Float16* __restrict__ w_all, _Float16* __restrict__ wo16,
    _Float16* __restrict__ aq, _Float16* __restrict__ ak, _Float16* __restrict__ av,
    const unsigned short* __restrict__ scu)
{
    int blk = blockIdx.x;
    if (blk < 512){
        int gid  = blk * 256 + threadIdx.x;          // 131072 threads, 8 elems
        int idx8 = gid * 8;
        int which = idx8 >> 18;                      // 262144 elems per matrix
        int rem   = idx8 & 262143;
        const unsigned short* W = (which==0)? Wq : (which==1)? Wk : (which==2)? Wv : Wo;
        float sw = b2f((which<3) ? scu[2 + 2*which] : scu[13]);
        ushort8 w = *(const ushort8*)(W + rem);
        half8 o;
        #pragma unroll
        for (int j=0;j<8;j++)
            o[j] = (_Float16)rintf(clampf(b2f(w[j])/sw, -128.f, 127.f));
        _Float16* dst = (which<3) ? (w_all + which*262144 + rem) : (wo16 + rem);
        *(half8*)dst = o;
    } else {
        int gid = (blk - 512) * 256 + threadIdx.x;   // 524288 threads, 8 elems
        int i8 = gid * 8;
        float s0 = b2f(scu[0]), s1 = b2f(scu[1]), s3 = b2f(scu[3]), s5 = b2f(scu[5]);
        ushort8 h = *(const ushort8*)(hs + i8);
        half8 q, k, v;
        #pragma unroll
        for (int j=0;j<8;j++){
            float h1 = rintf(clampf(b2f(h[j])/s0, -128.f, 127.f)) * s0;  // fq(hs,s0)
            q[j] = (_Float16)rintf(clampf(h1/s1, -128.f, 127.f));
            k[j] = (_Float16)rintf(clampf(h1/s3, -128.f, 127.f));
            v[j] = (_Float16)rintf(clampf(h1/s5, -128.f, 127.f));
        }
        *(half8*)(aq+i8) = q;
        *(half8*)(ak+i8) = k;
        *(half8*)(av+i8) = v;
    }
}

// ---------------------------------------------------------------------------
// QKV projection: M=8192, N=1536, K=512. 128x64 tiles, grid (64,24) = 1536
// blocks = 6 blocks/CU. V (proj==2) epilogue via LDS transpose (coalesced).
__global__ __launch_bounds__(256) void k_gemm_qkv(
    const _Float16* __restrict__ aq, const _Float16* __restrict__ ak,
    const _Float16* __restrict__ av, const _Float16* __restrict__ w_all,
    _Float16* __restrict__ q16, _Float16* __restrict__ k16, _Float16* __restrict__ vt16,
    const unsigned short* __restrict__ scu)
{
    __shared__ __align__(16) union SMem {
        struct { _Float16 At[128][64]; _Float16 Bt[64][64]; } ab;
        _Float16 Vt[64][132];            // +4 pad: conflict-free transpose
    } sm;
    int tid = threadIdx.x;
    int m0 = blockIdx.x*128, n0 = blockIdx.y*64;
    int proj = blockIdx.y >> 3;                  // 8 n-blocks of 64 per projection
    const _Float16* Ag = (proj==0)? aq : (proj==1)? ak : av;
    int w = tid>>6, lane = tid&63, l15 = lane&15, quad = lane>>4;
    int wm = w>>1, wn = w&1;
    f32x4 z = {0.f,0.f,0.f,0.f};
    f32x4 acc[4][2];
    #pragma unroll
    for (int i=0;i<4;i++)
      #pragma unroll
      for (int j=0;j<2;j++) acc[i][j] = z;

    for (int k0=0; k0<512; k0+=64){
        #pragma unroll
        for (int it=0; it<4; it++){          // A: 128x64 halves = 1024 x 16B
            int idx = it*256 + tid;
            int row = idx>>3, col = (idx&7)*8;
            int ubase = (it*256 + w*64)*8;   // wave-uniform LDS half-offset
            gld_lds16(Ag + (m0+row)*512 + k0 + col, &sm.ab.At[0][0] + ubase);
        }
        #pragma unroll
        for (int it=0; it<2; it++){          // B: 64x64 halves = 512 x 16B
            int idx = it*256 + tid;
            int row = idx>>3, col = (idx&7)*8;
            int ubase = (it*256 + w*64)*8;
            gld_lds16(w_all + (n0+row)*512 + k0 + col, &sm.ab.Bt[0][0] + ubase);
        }
        __syncthreads();
        half8 af[4][2], bf[2][2];
        #pragma unroll
        for (int mt=0; mt<4; mt++){
            af[mt][0] = *(const half8*)(&sm.ab.At[wm*64+mt*16+l15][quad*8]);
            af[mt][1] = *(const half8*)(&sm.ab.At[wm*64+mt*16+l15][32+quad*8]);
        }
        #pragma unroll
        for (int nt=0; nt<2; nt++){
            bf[nt][0] = *(const half8*)(&sm.ab.Bt[wn*32+nt*16+l15][quad*8]);
            bf[nt][1] = *(const half8*)(&sm.ab.Bt[wn*32+nt*16+l15][32+quad*8]);
        }
        #pragma unroll
        for (int mt=0; mt<4; mt++)
          #pragma unroll
          for (int nt=0; nt<2; nt++){
            acc[mt][nt] = __builtin_amdgcn_mfma_f32_16x16x32_f16(af[mt][0], bf[nt][0], acc[mt][nt], 0,0,0);
            acc[mt][nt] = __builtin_amdgcn_mfma_f32_16x16x32_f16(af[mt][1], bf[nt][1], acc[mt][nt], 0,0,0);
          }
        __syncthreads();
    }

    float ssc = b2f(scu[1+2*proj]) * b2f(scu[2+2*proj]);
    float qs  = b2f((proj==0)? scu[7] : (proj==1)? scu[8] : scu[11]);
    if (proj < 2){
        #pragma unroll
        for (int mt=0; mt<4; mt++){
          #pragma unroll
          for (int nt=0; nt<2; nt++){
            int n = n0 + wn*32 + nt*16 + l15;        // C/D col = lane&15 (verified)
            int nloc = n & 511;
            int h = nloc>>6, d = nloc&63;
            #pragma unroll
            for (int r=0;r<4;r++){
              int m = m0 + wm*64 + mt*16 + quad*4 + r;   // C/D row = quad*4+reg
              int b = m>>11, s = m&2047;
              int bh = b*8 + h;
              float val = acc[mt][nt][r] * ssc;
              float qv = rintf(clampf(val/qs, -128.f, 127.f));
              if (proj==0) q16[(bh*2048 + s)*64 + d] = (_Float16)qv;
              else         k16[(bh*2048 + s)*64 + d] = (_Float16)qv;
            }
          }
        }
    } else {
        // stage quantized V-tile into LDS transposed: Vt[n_local][m_local]
        #pragma unroll
        for (int mt=0; mt<4; mt++){
          #pragma unroll
          for (int nt=0; nt<2; nt++){
            int nl = wn*32 + nt*16 + l15;            // n-local 0..63
            #pragma unroll
            for (int r=0;r<4;r++){
              int ml = wm*64 + mt*16 + quad*4 + r;   // m-local 0..127
              float val = acc[mt][nt][r] * ssc;
              sm.Vt[nl][ml] = (_Float16)rintf(clampf(val/qs, -128.f, 127.f));
            }
          }
        }
        __syncthreads();
        int vrow = tid >> 2;                 // 0..63 (n-local)
        int vcol = (tid & 3) * 32;           // m-local base
        int nloc2 = (n0 & 511) + vrow;
        int h2 = nloc2 >> 6, d2 = nloc2 & 63;
        int bh2 = (m0 >> 11)*8 + h2;
        int s2 = (m0 & 2047) + vcol;
        _Float16* dst = vt16 + (bh2*64 + d2)*2048 + s2;
        #pragma unroll
        for (int i=0;i<4;i++)
            *(half8*)(dst + i*8) = *(const half8*)(&sm.Vt[vrow][vcol + i*8]);
    }
}

// ---------------------------------------------------------------------------
// Fused attention (R15 structure — best measured: 54.7 us). Pass-1 tracks
// per-chunk wave-max raw scores (cmx[32], unrolled — R4 rule); a provable
// mask then marks chunks that can yield nonzero quantized P:
//   needed  iff  fma(cmx[ch], al2, lq9max) > -1.0 - 1e-4
// (monotone chain: exp2(x)<=0.5 -> rint(p/s9)=0; skipped chunks provably
// all-zero — output bit-identical). Pass 2: barrier-free masked loop with
// direct-global K reads (L2-hot from pass 1).
// R16 lesson: do NOT split this kernel with tighter launch bounds — at
// (256,6) the register cap forces ~240 MB of scratch spill (WRITE_SIZE).
__global__ __launch_bounds__(256, 5) void k_attn(
    const _Float16* __restrict__ q16, const _Float16* __restrict__ k16,
    const _Float16* __restrict__ vt16, _Float16* __restrict__ o16,
    const unsigned short* __restrict__ scu)
{
    __shared__ __align__(16) _Float16 Kbuf[2][64][72];   // +8 pad (b128-aligned rows)
    __shared__ __align__(16) _Float16 p16[4][16][72];    // per-wave P staging
    int tid = threadIdx.x;
    int w = tid>>6, lane = tid&63, l15 = lane&15, quad = lane>>4;
    int bh = blockIdx.y;
    int q0 = blockIdx.x*64 + w*16;
    float s9 = b2f(scu[9]), s10 = b2f(scu[10]);
    float al2 = b2f(scu[7]) * b2f(scu[8]) * 0.125f * 1.44269504088896341f;

    f32x4 z = {0.f,0.f,0.f,0.f};
    const _Float16* qr = q16 + (bh*2048 + q0 + l15)*64;
    half8 aq0 = *(const half8*)(qr + quad*8);
    half8 aq1 = *(const half8*)(qr + 32 + quad*8);

    const _Float16* kg    = k16  + bh*131072;
    const _Float16* vbase = vt16 + bh*131072;
    int srow = tid>>3, scol = (tid&7)*8;

    half8 kst[2];
    #pragma unroll
    for (int i=0;i<2;i++) kst[i] = *(const half8*)(kg + i*2048 + tid*8);  // chunk 0

    float l[4] = {0.f, 0.f, 0.f, 0.f};
    float cmx[32];                           // per-chunk per-lane max raw score

    // ---- pass 1: denominator sums + per-chunk maxima (UNROLLED: cmx regs) ----
    #pragma unroll
    for (int ch=0; ch<32; ch++){
        int buf = ch & 1;
        #pragma unroll
        for (int i=0;i<2;i++) *(half8*)(&Kbuf[buf][srow + i*32][scol]) = kst[i];
        __syncthreads();
        if (ch < 31){                        // prefetch after barrier
            const _Float16* nsrc = kg + (ch+1)*4096;
            #pragma unroll
            for (int i=0;i<2;i++) kst[i] = *(const half8*)(nsrc + i*2048 + tid*8);
        }
        f32x4 s[4];
        #pragma unroll
        for (int j=0;j<4;j++){
            half8 bk0 = *(const half8*)(&Kbuf[buf][j*16+l15][quad*8]);
            half8 bk1 = *(const half8*)(&Kbuf[buf][j*16+l15][32+quad*8]);
            f32x4 t = __builtin_amdgcn_mfma_f32_16x16x32_f16(aq0, bk0, z, 0,0,0);
            s[j]    = __builtin_amdgcn_mfma_f32_16x16x32_f16(aq1, bk1, t, 0,0,0);
        }
        float mx = s[0][0];
        #pragma unroll
        for (int j=0;j<4;j++){
            #pragma unroll
            for (int r=0;r<4;r++){
                mx = fmaxf(mx, s[j][r]);
                l[r] += fexp2(s[j][r]*al2);
            }
        }
        cmx[ch] = mx;
    }

    #pragma unroll
    for (int r=0;r<4;r++){
        #pragma unroll
        for (int d=1; d<16; d<<=1)
            l[r] += __shfl_xor(l[r], d, 64);
    }
    float inv_s9 = 1.0f / s9;
    float r910   = s9 / s10;
    float lq9[4];
    #pragma unroll
    for (int r=0;r<4;r++) lq9[r] = log2f(inv_s9 / l[r]);
    // wave-max of lq9 over the 16 rows (rows live on quad; cols share values)
    float lm = fmaxf(fmaxf(lq9[0], lq9[1]), fmaxf(lq9[2], lq9[3]));
    lm = fmaxf(lm, __shfl_xor(lm, 16, 64));
    lm = fmaxf(lm, __shfl_xor(lm, 32, 64));
    // per-chunk needed mask (wave-uniform after full-lane max reduce)
    unsigned int mask = 0u;
    #pragma unroll
    for (int ch=0; ch<32; ch++){
        float cm = cmx[ch];
        #pragma unroll
        for (int d=1; d<64; d<<=1) cm = fmaxf(cm, __shfl_xor(cm, d, 64));
        if (fmaf(cm, al2, lm) > -1.0001f) mask |= (1u << ch);
    }

    // ---- pass 2: only masked chunks; direct global K loads; no barriers ----
    f32x4 oacc[4];
    #pragma unroll
    for (int dt=0; dt<4; dt++) oacc[dt] = z;
    for (int ch=0; ch<32; ch++){
        if (!(mask & (1u << ch))) continue;
        const _Float16* kc = kg + ch*4096;
        f32x4 s[4];
        #pragma unroll
        for (int j=0;j<4;j++){
            const _Float16* kr = kc + (j*16+l15)*64;
            half8 bk0 = *(const half8*)(kr + quad*8);
            half8 bk1 = *(const half8*)(kr + 32 + quad*8);
            f32x4 t = __builtin_amdgcn_mfma_f32_16x16x32_f16(aq0, bk0, z, 0,0,0);
            s[j]    = __builtin_amdgcn_mfma_f32_16x16x32_f16(aq1, bk1, t, 0,0,0);
        }
        float av[4][4];
        float amax = 0.f;
        #pragma unroll
        for (int j=0;j<4;j++){
            #pragma unroll
            for (int r=0;r<4;r++){
                float p1i = rintf(fminf(fexp2(fmaf(s[j][r], al2, lq9[r])), 255.f));
                float a   = rintf(fminf(p1i*r910, 127.f));
                av[j][r] = a;
                amax = fmaxf(amax, a);
            }
        }
        if (__ballot(amax > 0.f)){           // bound not tight: exact re-check
            #pragma unroll
            for (int j=0;j<4;j++)
                #pragma unroll
                for (int r=0;r<4;r++)
                    p16[w][quad*4+r][j*16+l15] = (_Float16)av[j][r];
            half8 ap0 = *(const half8*)(&p16[w][l15][quad*8]);
            half8 ap1 = *(const half8*)(&p16[w][l15][32+quad*8]);
            #pragma unroll
            for (int dt=0; dt<4; dt++){
                const _Float16* vr0 = vbase + (dt*16+l15)*2048 + ch*64;
                half8 b0 = *(const half8*)(vr0 + quad*8);
                half8 b1 = *(const half8*)(vr0 + 32 + quad*8);
                oacc[dt] = __builtin_amdgcn_mfma_f32_16x16x32_f16(ap0, b0, oacc[dt], 0,0,0);
                oacc[dt] = __builtin_amdgcn_mfma_f32_16x16x32_f16(ap1, b1, oacc[dt], 0,0,0);
            }
        }
    }

    // ---- epilogue: quantize with sc12, direct C-layout stores ----
    float s1011 = b2f(scu[10]) * b2f(scu[11]);
    float s12   = b2f(scu[12]);
    int b = bh>>3, h = bh&7;
    #pragma unroll
    for (int dt=0; dt<4; dt++){
        #pragma unroll
        for (int r=0;r<4;r++){
            float o = oacc[dt][r] * s1011;
            _Float16 v = (_Float16)rintf(clampf(o/s12, -128.f, 127.f));
            o16[(b*2048 + q0 + quad*4 + r)*512 + h*64 + dt*16 + l15] = v;
        }
    }
}

// ---------------------------------------------------------------------------
// Output projection: M=8192, N=512, K=512, + bias, bf16 out. 64x64 tiles.
__global__ __launch_bounds__(256) void k_gemm_out(
    const _Float16* __restrict__ o16, const _Float16* __restrict__ wo16,
    const unsigned short* __restrict__ bo, unsigned short* __restrict__ out,
    const unsigned short* __restrict__ scu)
{
    __shared__ __align__(16) _Float16 At[64][64];
    __shared__ __align__(16) _Float16 Bt[64][64];
    int tid = threadIdx.x;
    int m0 = blockIdx.x*64, n0 = blockIdx.y*64;
    int w = tid>>6, lane = tid&63, l15 = lane&15, quad = lane>>4;
    int wm = w>>1, wn = w&1;
    f32x4 z = {0.f,0.f,0.f,0.f};
    f32x4 acc[2][2];
    #pragma unroll
    for (int i=0;i<2;i++)
      #pragma unroll
      for (int j=0;j<2;j++) acc[i][j] = z;

    for (int k0=0; k0<512; k0+=64){
        #pragma unroll
        for (int it=0; it<2; it++){
            int idx = it*256 + tid;
            int row = idx>>3, col = (idx&7)*8;
            int ubase = (it*256 + w*64)*8;
            gld_lds16(o16  + (m0+row)*512 + k0 + col, &At[0][0] + ubase);
        }
        #pragma unroll
        for (int it=0; it<2; it++){
            int idx = it*256 + tid;
            int row = idx>>3, col = (idx&7)*8;
            int ubase = (it*256 + w*64)*8;
            gld_lds16(wo16 + (n0+row)*512 + k0 + col, &Bt[0][0] + ubase);
        }
        __syncthreads();
        half8 af[2][2], bf[2][2];
        #pragma unroll
        for (int mt=0; mt<2; mt++){
            af[mt][0] = *(const half8*)(&At[wm*32+mt*16+l15][quad*8]);
            af[mt][1] = *(const half8*)(&At[wm*32+mt*16+l15][32+quad*8]);
        }
        #pragma unroll
        for (int nt=0; nt<2; nt++){
            bf[nt][0] = *(const half8*)(&Bt[wn*32+nt*16+l15][quad*8]);
            bf[nt][1] = *(const half8*)(&Bt[wn*32+nt*16+l15][32+quad*8]);
        }
        #pragma unroll
        for (int mt=0; mt<2; mt++)
          #pragma unroll
          for (int nt=0; nt<2; nt++){
            acc[mt][nt] = __builtin_amdgcn_mfma_f32_16x16x32_f16(af[mt][0], bf[nt][0], acc[mt][nt], 0,0,0);
            acc[mt][nt] = __builtin_amdgcn_mfma_f32_16x16x32_f16(af[mt][1], bf[nt][1], acc[mt][nt], 0,0,0);
          }
        __syncthreads();
    }

    float ssc = b2f(scu[12]) * b2f(scu[13]);
    #pragma unroll
    for (int mt=0; mt<2; mt++){
      #pragma unroll
      for (int nt=0; nt<2; nt++){
        int n = n0 + wn*32 + nt*16 + l15;
        float bn = b2f(bo[n]);
        #pragma unroll
        for (int r=0;r<4;r++){
          int m = m0 + wm*32 + mt*16 + quad*4 + r;
          out[m*512 + n] = f2b(acc[mt][nt][r]*ssc + bn);
        }
      }
    }
}

// ---------------------------------------------------------------------------
extern "C" void kernel_launch(void* const* d_in, const int* in_sizes, int n_in,
                              void* d_out, int out_size, void* d_ws, size_t ws_size,
                              hipStream_t stream)
{
    const unsigned short* hs = (const unsigned short*)d_in[0];
    const unsigned short* Wq = (const unsigned short*)d_in[1];
    const unsigned short* Wk = (const unsigned short*)d_in[2];
    const unsigned short* Wv = (const unsigned short*)d_in[3];
    const unsigned short* Wo = (const unsigned short*)d_in[4];
    const unsigned short* bo = (const unsigned short*)d_in[5];
    const unsigned short* sc = (const unsigned short*)d_in[6];
    unsigned short* out = (unsigned short*)d_out;

    _Float16* wsh   = (_Float16*)d_ws;
    _Float16* w_all = wsh + EW_WALL;
    _Float16* wo16  = wsh + EW_WO;
    _Float16* a_q   = wsh + EW_AQ;
    _Float16* a_k   = wsh + EW_AK;
    _Float16* a_v   = wsh + EW_AV;
    _Float16* q16   = wsh + EW_Q;
    _Float16* k16   = wsh + EW_K;
    _Float16* vt16  = wsh + EW_VT;
    _Float16* o16   = wsh + EW_O;

    k_quant<<<2560, 256, 0, stream>>>(hs, Wq, Wk, Wv, Wo, w_all, wo16,
                                      a_q, a_k, a_v, sc);
    k_gemm_qkv<<<dim3(64,24), 256, 0, stream>>>(a_q, a_k, a_v, w_all, q16, k16, vt16, sc);
    k_attn<<<dim3(32,32), 256, 0, stream>>>(q16, k16, vt16, o16, sc);
    k_gemm_out<<<dim3(128,8), 256, 0, stream>>>(o16, wo16, bo, out, sc);
}